// Round 11
// baseline (154.317 us; speedup 1.0000x reference)
//
#include <hip/hip_runtime.h>

// AdditiveAttention: B=4, Q=256, K=1024, DQ=DK=DV=512, H=128
#define B_ 4
#define Q_ 256
#define K_ 1024
#define D_ 512
#define H_ 128
#define DV_ 512
#define LOG2E 1.4426950408889634f

// Clamped Pade[7/6] tanh: err <= ~5e-4, 11 VALU + 1 rcp (med3 clamp).
__device__ __forceinline__ float tanh_pade(float x) {
    x = __builtin_amdgcn_fmed3f(x, -4.6f, 4.6f);
    float u = x * x;
    float p = fmaf(u, fmaf(u, 21.0f, 1260.0f), 10395.0f) * x;
    float qd = fmaf(u, fmaf(u, (u + 210.0f), 4725.0f), 10395.0f);
    return p * __builtin_amdgcn_rcpf(qd);
}

// ---------------------------------------------------------------------------
// proj_part: one (64-row tile, 64-d slice). Grid 640 = [ds:8 == bid&7][tile:80].
// ds is the XCD-aligned axis (uniform masking per d-slice). LDS 51 KB ->
// 3 blocks/CU. 4 waves = (32r x 64h) quadrants, lane micro 4x8. Partials ->
// psum. Block 0 zeroes the attn work-steal counter.
// ---------------------------------------------------------------------------
__global__ __launch_bounds__(256) void proj_part(
    const float* __restrict__ qin, const float* __restrict__ kin,
    const float* __restrict__ wq,  const float* __restrict__ wk,
    const int* __restrict__ valid_lens, float* __restrict__ psum,
    int* __restrict__ wcnt)
{
    __shared__ float Xs[64][68];     // 17.4 KB
    __shared__ float Ws[64][132];    // 33.8 KB

    const int t = threadIdx.x, bid = blockIdx.x;
    if (bid == 0 && t == 0) *wcnt = 0;          // arm attn work queue
    const int ds = bid & 7, tile = bid >> 3;    // tile 0..79
    const int d0 = ds * 64;
    const float* X; const float* W;
    if (tile < 16) { X = qin + (size_t)tile * 64 * D_; W = wq; }
    else {
        int kt = tile - 16, b = kt >> 4, kr = (kt & 15) * 64;
        if (kr >= valid_lens[b]) return;
        X = kin + ((size_t)b * K_ + kr) * D_;
        W = wk;
    }
    const int R0 = tile * 64;

#pragma unroll
    for (int i = 0; i < 4; ++i) {        // stage X: 64 r x 64 d
        int idx = t + i * 256;
        int row = idx >> 4, dq = (idx & 15) * 4;
        float4 xv = *(const float4*)&X[(size_t)row * D_ + d0 + dq];
        Xs[dq+0][row] = xv.x; Xs[dq+1][row] = xv.y;
        Xs[dq+2][row] = xv.z; Xs[dq+3][row] = xv.w;
    }
#pragma unroll
    for (int i = 0; i < 8; ++i) {        // stage W: 128 h x 64 d
        int idx = t + i * 256;
        int h = idx >> 4, dq = (idx & 15) * 4;
        float4 wv = *(const float4*)&W[(size_t)h * D_ + d0 + dq];
        Ws[dq+0][h] = wv.x; Ws[dq+1][h] = wv.y;
        Ws[dq+2][h] = wv.z; Ws[dq+3][h] = wv.w;
    }
    __syncthreads();

    const int wid = t >> 6, lane = t & 63;
    const int r0 = (wid >> 1) * 32 + (lane >> 3) * 4;
    const int h0 = (wid & 1)  * 64 + (lane & 7)  * 8;
    float c[4][8] = {};

#pragma unroll 4
    for (int kk = 0; kk < 64; ++kk) {
        float xr[4], wr[8];
        *(float4*)&xr[0] = *(const float4*)&Xs[kk][r0];
        *(float4*)&wr[0] = *(const float4*)&Ws[kk][h0];
        *(float4*)&wr[4] = *(const float4*)&Ws[kk][h0 + 4];
#pragma unroll
        for (int i = 0; i < 4; ++i)
#pragma unroll
            for (int j = 0; j < 8; ++j) c[i][j] += xr[i] * wr[j];
    }

    float* outp = psum + ((size_t)ds * 5120 + R0) * 128;
#pragma unroll
    for (int i = 0; i < 4; ++i) {
        *(float4*)&outp[(size_t)(r0 + i) * 128 + h0]     = *(const float4*)&c[i][0];
        *(float4*)&outp[(size_t)(r0 + i) * 128 + h0 + 4] = *(const float4*)&c[i][4];
    }
}

// ---------------------------------------------------------------------------
// proj_reduce: sum 8 d-slices, write qh_s / kh4 layouts. Masked k rows skip.
// ---------------------------------------------------------------------------
__global__ __launch_bounds__(256) void proj_reduce(
    const float* __restrict__ psum, const int* __restrict__ valid_lens,
    float* __restrict__ qh_s, float4* __restrict__ kh4)
{
    int gid = blockIdx.x * 256 + threadIdx.x;    // [0, 163840)
    int row = gid >> 5, c4 = gid & 31;
    int b = 0, kk = 0;
    if (row >= 1024) {
        int r = row - 1024;
        b = r >> 10; kk = r & 1023;
        if (kk >= valid_lens[b]) return;
    }
    float4 s = make_float4(0.f, 0.f, 0.f, 0.f);
#pragma unroll
    for (int ds = 0; ds < 8; ++ds) {
        float4 v = *(const float4*)&psum[((size_t)ds * 5120 + row) * 128 + c4 * 4];
        s.x += v.x; s.y += v.y; s.z += v.z; s.w += v.w;
    }
    if (row < 1024) *(float4*)&qh_s[(size_t)row * 128 + c4 * 4] = s;
    else            kh4[((size_t)(b * 32 + c4)) * K_ + kk] = s;
}

// ---------------------------------------------------------------------------
// attn_part: persistent work-stealing over a COMPACTED item list.
// 1024 blocks x 256 thr (4 waves; 29.7 KB LDS -> 4 blocks/CU = 16 waves/CU,
// the round-10 512-block version sat at 1 block/CU = latency-exposed).
// Items: s = c*32 + qt, c in [0,Tc) where Tc = sum_b ceil(vl_b/128) — only
// ACTIVE chunks (no wasted steals, tail = 1 item). c -> (b,kc) via 4-entry
// prefix computed from valid_lens by every block.
// Body unchanged: Phase B Pade scores (hh-halves, kh prefetch depth 1),
// exp without max-pass (|score| <= Sum|w_v| ~ 5, exp2 safe; softmax is
// shift-invariant), Phase D partial PV with v prefetch; private o_part[kc]
// slices; no atomics in the data path.
// ---------------------------------------------------------------------------
__global__ __launch_bounds__(256) void attn_part(
    const float* __restrict__ qh_s, const float4* __restrict__ kh4,
    const float* __restrict__ wvg,  const int* __restrict__ valid_lens,
    const float* __restrict__ vin,  int* __restrict__ wcnt,
    float* __restrict__ s_part, float4* __restrict__ o_part)
{
    __shared__ float  qv[1024];
    __shared__ float  wvs[128];
    __shared__ float  ptmp[8][128];
    __shared__ float  p[8][128];
    __shared__ float  sred[2][8];
    __shared__ float4 otmp[8][128];
    __shared__ int    sidx;

    const int t = threadIdx.x;
    if (t < 128) wvs[t] = wvg[t];

    const int vl0 = valid_lens[0], vl1 = valid_lens[1];
    const int vl2 = valid_lens[2], vl3 = valid_lens[3];
    const int n0 = (vl0 + 127) >> 7, n1 = (vl1 + 127) >> 7;
    const int n2 = (vl2 + 127) >> 7, n3 = (vl3 + 127) >> 7;
    const int p1 = n0 + n1, p2 = p1 + n2, Tc = p2 + n3;
    const int T  = Tc << 5;

    for (;;) {
        __syncthreads();                 // sidx + LDS reuse fence
        if (t == 0) sidx = atomicAdd(wcnt, 1);
        __syncthreads();
        const int idx = sidx;
        if (idx >= T) break;

        const int qt = idx & 31, c = idx >> 5;
        int b, kc;
        if      (c < n0) { b = 0; kc = c;      }
        else if (c < p1) { b = 1; kc = c - n0; }
        else if (c < p2) { b = 2; kc = c - p1; }
        else             { b = 3; kc = c - p2; }
        const int q0 = qt * 8;
        const int vl = valid_lens[b];
        const int kbase = kc * 128;
        const int klen = min(128, vl - kbase);

#pragma unroll
        for (int i = 0; i < 4; ++i)
            qv[t + i * 256] = qh_s[(size_t)(b*Q_ + q0) * H_ + t + i * 256];
        __syncthreads();

        const int k  = t & 127;
        const int hh = t >> 7;
        const bool active = k < klen;

        // ---- Phase B: scores ----
        float acc[8] = {};
        if (active) {
            const float4* khp = kh4 + (size_t)b * 32 * K_ + (kbase + k)
                              + (size_t)(hh * 16) * K_;
            const int hq0 = hh * 16;
            float4 kxn = khp[0];
#pragma unroll 4
            for (int i = 0; i < 16; ++i) {
                float4 kx = kxn;
                int ni = (i < 15) ? i + 1 : 15;
                kxn = khp[(size_t)ni * K_];
                const int hq = hq0 + i;
                float w4[4], kxa[4];
                *(float4*)&w4[0]  = *(const float4*)&wvs[hq*4];
                *(float4*)&kxa[0] = kx;
#pragma unroll
                for (int qi = 0; qi < 8; ++qi) {
                    float q4[4];
                    *(float4*)&q4[0] = *(const float4*)&qv[qi*128 + hq*4];
#pragma unroll
                    for (int j = 0; j < 4; ++j)
                        acc[qi] += w4[j] * tanh_pade(q4[j] + kxa[j]);
                }
            }
        }
        if (hh == 1) {
#pragma unroll
            for (int qi = 0; qi < 8; ++qi) ptmp[qi][k] = acc[qi];
        }
        __syncthreads();

        if (hh == 0) {
            float psum8[8];
#pragma unroll
            for (int qi = 0; qi < 8; ++qi) {
                float a = acc[qi] + ptmp[qi][k];
                float e = active ? __builtin_amdgcn_exp2f(a * LOG2E) : 0.f;
                p[qi][k] = e;
                psum8[qi] = e;
            }
#pragma unroll
            for (int off = 32; off > 0; off >>= 1)
#pragma unroll
                for (int qi = 0; qi < 8; ++qi) psum8[qi] += __shfl_xor(psum8[qi], off);
            if ((t & 63) == 0) {
#pragma unroll
                for (int qi = 0; qi < 8; ++qi) sred[t >> 6][qi] = psum8[qi];
            }
        }
        __syncthreads();                 // p + sred ready
        if (t < 8)
            s_part[(size_t)(b*Q_ + q0 + t) * 8 + kc] = sred[0][t] + sred[1][t];

        // ---- Phase D: partial PV ----
        const int col  = t & 127;
        const int half = t >> 7;
        const int kb2  = half * 64;
        const int ke2  = min(klen, kb2 + 64);
        const float4* vb = (const float4*)vin + (size_t)b * K_ * 128
                         + (size_t)kbase * 128;

        float4 o[8];
#pragma unroll
        for (int qi = 0; qi < 8; ++qi) o[qi] = make_float4(0.f, 0.f, 0.f, 0.f);

        int kk = kb2;
        const int nfull = (ke2 > kb2) ? ((ke2 - kb2) >> 2) : 0;
        if (nfull > 0) {
            float4 n0v = vb[(size_t)(kk+0)*128 + col];
            float4 n1v = vb[(size_t)(kk+1)*128 + col];
            float4 n2v = vb[(size_t)(kk+2)*128 + col];
            float4 n3v = vb[(size_t)(kk+3)*128 + col];
            for (int g = 0; g < nfull; ++g) {
                float4 v0 = n0v, v1 = n1v, v2 = n2v, v3 = n3v;
                int kn = kk + 4;
                if (g + 1 < nfull) {
                    n0v = vb[(size_t)(kn+0)*128 + col];
                    n1v = vb[(size_t)(kn+1)*128 + col];
                    n2v = vb[(size_t)(kn+2)*128 + col];
                    n3v = vb[(size_t)(kn+3)*128 + col];
                }
#pragma unroll
                for (int qi = 0; qi < 8; ++qi) {
                    float4 pq = *(const float4*)&p[qi][kk];
                    o[qi].x += pq.x*v0.x + pq.y*v1.x + pq.z*v2.x + pq.w*v3.x;
                    o[qi].y += pq.x*v0.y + pq.y*v1.y + pq.z*v2.y + pq.w*v3.y;
                    o[qi].z += pq.x*v0.z + pq.y*v1.z + pq.z*v2.z + pq.w*v3.z;
                    o[qi].w += pq.x*v0.w + pq.y*v1.w + pq.z*v2.w + pq.w*v3.w;
                }
                kk = kn;
            }
        }
        for (; kk < ke2; ++kk) {
            float4 v0 = vb[(size_t)kk*128 + col];
#pragma unroll
            for (int qi = 0; qi < 8; ++qi) {
                float pk = p[qi][kk];
                o[qi].x += pk*v0.x; o[qi].y += pk*v0.y;
                o[qi].z += pk*v0.z; o[qi].w += pk*v0.w;
            }
        }

        if (half == 1) {
#pragma unroll
            for (int qi = 0; qi < 8; ++qi) otmp[qi][col] = o[qi];
        }
        __syncthreads();
        if (half == 0) {
#pragma unroll
            for (int qi = 0; qi < 8; ++qi) {
                float4 r = otmp[qi][col];
                o[qi].x += r.x; o[qi].y += r.y; o[qi].z += r.z; o[qi].w += r.w;
                o_part[((size_t)kc * 1024 + (b*Q_ + q0 + qi)) * 128 + col] = o[qi];
            }
        }
    }
}

// ---------------------------------------------------------------------------
// finalize: out[row][col] = (Sum_{ch<nch} o_part[ch][row][col]) * rcp(Sum s).
// ---------------------------------------------------------------------------
__global__ __launch_bounds__(256) void finalize_kernel(
    const float4* __restrict__ o_part, const float* __restrict__ s_part,
    const int* __restrict__ valid_lens, float4* __restrict__ out)
{
    int gid = blockIdx.x * 256 + threadIdx.x;     // [0, 131072)
    int row = gid >> 7, col = gid & 127;
    int b = row >> 8;
    int nch = (valid_lens[b] + 127) >> 7;
    float ssum = 0.f;
    float4 o = make_float4(0.f, 0.f, 0.f, 0.f);
    for (int ch = 0; ch < nch; ++ch) {
        ssum += s_part[(size_t)row * 8 + ch];
        float4 r = o_part[((size_t)ch * 1024 + row) * 128 + col];
        o.x += r.x; o.y += r.y; o.z += r.z; o.w += r.w;
    }
    float rs = __builtin_amdgcn_rcpf(ssum);
    out[gid] = make_float4(o.x*rs, o.y*rs, o.z*rs, o.w*rs);
}

extern "C" void kernel_launch(void* const* d_in, const int* in_sizes, int n_in,
                              void* d_out, int out_size, void* d_ws, size_t ws_size,
                              hipStream_t stream)
{
    const float* q  = (const float*)d_in[0];
    const float* k  = (const float*)d_in[1];
    const float* v  = (const float*)d_in[2];
    const int*   vl = (const int*)d_in[3];
    const float* wq = (const float*)d_in[4];
    const float* wk = (const float*)d_in[5];
    const float* wv = (const float*)d_in[6];
    float* out = (float*)d_out;

    float* qh_s  = (float*)d_ws;                      //  131072 f
    float* kh4   = qh_s  + (size_t)B_*Q_*H_;          //  524288 f
    float* s_prt = kh4   + (size_t)B_*H_*K_;          //    8192 f
    float* o_prt = s_prt + (size_t)B_*Q_*8;           // 4194304 f (16 MB)
    float* psum  = o_prt + (size_t)8*B_*Q_*DV_;       // 5242880 f (21 MB)
    int*   wcnt  = (int*)(psum + (size_t)8*5120*128); // 1 int

    proj_part      <<<dim3(640),  dim3(256), 0, stream>>>(q, k, wq, wk, vl, psum, wcnt);
    proj_reduce    <<<dim3(640),  dim3(256), 0, stream>>>(psum, vl, qh_s, (float4*)kh4);
    attn_part      <<<dim3(1024), dim3(256), 0, stream>>>(qh_s, (const float4*)kh4, wv, vl, v, wcnt, s_prt, (float4*)o_prt);
    finalize_kernel<<<dim3(512),  dim3(256), 0, stream>>>((const float4*)o_prt, s_prt, vl, (float4*)out);
}

// Round 12
// 121.420 us; speedup vs baseline: 1.2709x; 1.2709x over previous
//
#include <hip/hip_runtime.h>

// AdditiveAttention: B=4, Q=256, K=1024, DQ=DK=DV=512, H=128
#define B_ 4
#define Q_ 256
#define K_ 1024
#define D_ 512
#define H_ 128
#define DV_ 512
#define LOG2E 1.4426950408889634f

// Clamped Pade[7/6] tanh: err <= ~5e-4, 11 VALU + 1 rcp (med3 clamp).
__device__ __forceinline__ float tanh_pade(float x) {
    x = __builtin_amdgcn_fmed3f(x, -4.6f, 4.6f);
    float u = x * x;
    float p = fmaf(u, fmaf(u, 21.0f, 1260.0f), 10395.0f) * x;
    float qd = fmaf(u, fmaf(u, (u + 210.0f), 4725.0f), 10395.0f);
    return p * __builtin_amdgcn_rcpf(qd);
}

// ---------------------------------------------------------------------------
// proj_part: one (64-row tile, 64-d slice). Grid 640 = [ds:8 == bid&7][tile:80].
// ds is the XCD-aligned axis (uniform masking per d-slice). LDS 51 KB ->
// 3 blocks/CU. 4 waves = (32r x 64h) quadrants, lane micro 4x8. Partials ->
// psum.
// ---------------------------------------------------------------------------
__global__ __launch_bounds__(256) void proj_part(
    const float* __restrict__ qin, const float* __restrict__ kin,
    const float* __restrict__ wq,  const float* __restrict__ wk,
    const int* __restrict__ valid_lens, float* __restrict__ psum)
{
    __shared__ float Xs[64][68];     // 17.4 KB
    __shared__ float Ws[64][132];    // 33.8 KB

    const int t = threadIdx.x, bid = blockIdx.x;
    const int ds = bid & 7, tile = bid >> 3;    // tile 0..79
    const int d0 = ds * 64;
    const float* X; const float* W;
    if (tile < 16) { X = qin + (size_t)tile * 64 * D_; W = wq; }
    else {
        int kt = tile - 16, b = kt >> 4, kr = (kt & 15) * 64;
        if (kr >= valid_lens[b]) return;
        X = kin + ((size_t)b * K_ + kr) * D_;
        W = wk;
    }
    const int R0 = tile * 64;

#pragma unroll
    for (int i = 0; i < 4; ++i) {        // stage X: 64 r x 64 d
        int idx = t + i * 256;
        int row = idx >> 4, dq = (idx & 15) * 4;
        float4 xv = *(const float4*)&X[(size_t)row * D_ + d0 + dq];
        Xs[dq+0][row] = xv.x; Xs[dq+1][row] = xv.y;
        Xs[dq+2][row] = xv.z; Xs[dq+3][row] = xv.w;
    }
#pragma unroll
    for (int i = 0; i < 8; ++i) {        // stage W: 128 h x 64 d
        int idx = t + i * 256;
        int h = idx >> 4, dq = (idx & 15) * 4;
        float4 wv = *(const float4*)&W[(size_t)h * D_ + d0 + dq];
        Ws[dq+0][h] = wv.x; Ws[dq+1][h] = wv.y;
        Ws[dq+2][h] = wv.z; Ws[dq+3][h] = wv.w;
    }
    __syncthreads();

    const int wid = t >> 6, lane = t & 63;
    const int r0 = (wid >> 1) * 32 + (lane >> 3) * 4;
    const int h0 = (wid & 1)  * 64 + (lane & 7)  * 8;
    float c[4][8] = {};

#pragma unroll 4
    for (int kk = 0; kk < 64; ++kk) {
        float xr[4], wr[8];
        *(float4*)&xr[0] = *(const float4*)&Xs[kk][r0];
        *(float4*)&wr[0] = *(const float4*)&Ws[kk][h0];
        *(float4*)&wr[4] = *(const float4*)&Ws[kk][h0 + 4];
#pragma unroll
        for (int i = 0; i < 4; ++i)
#pragma unroll
            for (int j = 0; j < 8; ++j) c[i][j] += xr[i] * wr[j];
    }

    float* outp = psum + ((size_t)ds * 5120 + R0) * 128;
#pragma unroll
    for (int i = 0; i < 4; ++i) {
        *(float4*)&outp[(size_t)(r0 + i) * 128 + h0]     = *(const float4*)&c[i][0];
        *(float4*)&outp[(size_t)(r0 + i) * 128 + h0 + 4] = *(const float4*)&c[i][4];
    }
}

// ---------------------------------------------------------------------------
// proj_reduce: sum 8 d-slices, write qh_s / kh4 layouts. Masked k rows skip.
// ---------------------------------------------------------------------------
__global__ __launch_bounds__(256) void proj_reduce(
    const float* __restrict__ psum, const int* __restrict__ valid_lens,
    float* __restrict__ qh_s, float4* __restrict__ kh4)
{
    int gid = blockIdx.x * 256 + threadIdx.x;    // [0, 163840)
    int row = gid >> 5, c4 = gid & 31;
    int b = 0, kk = 0;
    if (row >= 1024) {
        int r = row - 1024;
        b = r >> 10; kk = r & 1023;
        if (kk >= valid_lens[b]) return;
    }
    float4 s = make_float4(0.f, 0.f, 0.f, 0.f);
#pragma unroll
    for (int ds = 0; ds < 8; ++ds) {
        float4 v = *(const float4*)&psum[((size_t)ds * 5120 + row) * 128 + c4 * 4];
        s.x += v.x; s.y += v.y; s.z += v.z; s.w += v.w;
    }
    if (row < 1024) *(float4*)&qh_s[(size_t)row * 128 + c4 * 4] = s;
    else            kh4[((size_t)(b * 32 + c4)) * K_ + kk] = s;
}

// ---------------------------------------------------------------------------
// attn_part: STATIC oversubscribed grid, no atomics. 2048 blocks x 256 thr
// (4 waves), item = (b, 8-q tile, 64-k chunk). ~5 resident blocks/CU (28.7 KB
// LDS) + queued blocks let the HW dispatcher load-balance (round-10/11's
// global-counter work queue serialized at ~70+ cyc/steal on one L2 line —
// the dispatcher does the same job contention-free).
// Mapping: qt = bid&31 (XCD axis: uniform activity per XCD), co-resident
// slots (bid mod 256) span 2 kc x 4 b -> mixed active/inactive.
// Phase B: 4-way h-split (hh = t>>6, 8 hq each), kh prefetch depth 1,
// Pade tanh, 256 tanh/thread. No softmax max-pass (|score| <= Sum|w_v| ~ 5,
// exp2 safe; softmax shift-invariant). Phase D: 2-way k-split over 32 k,
// v prefetch; private o_part[kc] slices (16 slices of 64 k).
// ---------------------------------------------------------------------------
__global__ __launch_bounds__(256) void attn_part(
    const float* __restrict__ qh_s, const float4* __restrict__ kh4,
    const float* __restrict__ wvg,  const int* __restrict__ valid_lens,
    const float* __restrict__ vin,
    float* __restrict__ s_part, float4* __restrict__ o_part)
{
    __shared__ float  qv[1024];
    __shared__ float  wvs[128];
    __shared__ float  ptmp[3][8][64];
    __shared__ float  p[8][64];
    __shared__ float4 otmp[8][128];

    const int t   = threadIdx.x;
    const int bid = blockIdx.x;
    const int qt  = bid & 31, kc = (bid >> 5) & 15, b = bid >> 9;
    const int q0  = qt * 8;
    const int vl  = valid_lens[b];
    const int kbase = kc * 64;
    if (kbase >= vl) return;
    const int klen = min(64, vl - kbase);

#pragma unroll
    for (int i = 0; i < 4; ++i)
        qv[t + i * 256] = qh_s[(size_t)(b*Q_ + q0) * H_ + t + i * 256];
    if (t < 128) wvs[t] = wvg[t];
    __syncthreads();

    const int k  = t & 63;              // k within chunk
    const int hh = t >> 6;              // h-quarter (== wave id)
    const bool active = k < klen;

    // ---- Phase B: scores (4-way h-split, kh prefetch depth 1) ----
    float acc[8] = {};
    if (active) {
        const float4* khp = kh4 + (size_t)b * 32 * K_ + (kbase + k)
                          + (size_t)(hh * 8) * K_;
        const int hq0 = hh * 8;
        float4 kxn = khp[0];
#pragma unroll
        for (int i = 0; i < 8; ++i) {
            float4 kx = kxn;
            int ni = (i < 7) ? i + 1 : 7;
            kxn = khp[(size_t)ni * K_];
            const int hq = hq0 + i;
            float w4[4], kxa[4];
            *(float4*)&w4[0]  = *(const float4*)&wvs[hq*4];
            *(float4*)&kxa[0] = kx;
#pragma unroll
            for (int qi = 0; qi < 8; ++qi) {
                float q4[4];
                *(float4*)&q4[0] = *(const float4*)&qv[qi*128 + hq*4];
#pragma unroll
                for (int j = 0; j < 4; ++j)
                    acc[qi] += w4[j] * tanh_pade(q4[j] + kxa[j]);
            }
        }
    }
    if (hh != 0) {
#pragma unroll
        for (int qi = 0; qi < 8; ++qi) ptmp[hh-1][qi][k] = acc[qi];
    }
    __syncthreads();

    if (hh == 0) {
        float psum8[8];
#pragma unroll
        for (int qi = 0; qi < 8; ++qi) {
            float a = acc[qi] + ptmp[0][qi][k] + ptmp[1][qi][k] + ptmp[2][qi][k];
            float e = active ? __builtin_amdgcn_exp2f(a * LOG2E) : 0.f;
            p[qi][k] = e;
            psum8[qi] = e;
        }
#pragma unroll
        for (int off = 32; off > 0; off >>= 1)
#pragma unroll
            for (int qi = 0; qi < 8; ++qi) psum8[qi] += __shfl_xor(psum8[qi], off);
        if (t == 0) {
#pragma unroll
            for (int qi = 0; qi < 8; ++qi)
                s_part[(size_t)(b*Q_ + q0 + qi) * 16 + kc] = psum8[qi];
        }
    }
    __syncthreads();                    // p ready

    // ---- Phase D: partial PV (2-way k-split, v prefetch one 4-group) ----
    const int col  = t & 127;           // float4 column of DV/4
    const int half = t >> 7;
    const int kb2  = half * 32;
    const int ke2  = min(klen, kb2 + 32);
    const float4* vb = (const float4*)vin + (size_t)b * K_ * 128
                     + (size_t)kbase * 128;

    float4 o[8];
#pragma unroll
    for (int qi = 0; qi < 8; ++qi) o[qi] = make_float4(0.f, 0.f, 0.f, 0.f);

    int kk = kb2;
    const int nfull = (ke2 > kb2) ? ((ke2 - kb2) >> 2) : 0;
    if (nfull > 0) {
        float4 n0v = vb[(size_t)(kk+0)*128 + col];
        float4 n1v = vb[(size_t)(kk+1)*128 + col];
        float4 n2v = vb[(size_t)(kk+2)*128 + col];
        float4 n3v = vb[(size_t)(kk+3)*128 + col];
        for (int g = 0; g < nfull; ++g) {
            float4 v0 = n0v, v1 = n1v, v2 = n2v, v3 = n3v;
            int kn = kk + 4;
            if (g + 1 < nfull) {
                n0v = vb[(size_t)(kn+0)*128 + col];
                n1v = vb[(size_t)(kn+1)*128 + col];
                n2v = vb[(size_t)(kn+2)*128 + col];
                n3v = vb[(size_t)(kn+3)*128 + col];
            }
#pragma unroll
            for (int qi = 0; qi < 8; ++qi) {
                float4 pq = *(const float4*)&p[qi][kk];
                o[qi].x += pq.x*v0.x + pq.y*v1.x + pq.z*v2.x + pq.w*v3.x;
                o[qi].y += pq.x*v0.y + pq.y*v1.y + pq.z*v2.y + pq.w*v3.y;
                o[qi].z += pq.x*v0.z + pq.y*v1.z + pq.z*v2.z + pq.w*v3.z;
                o[qi].w += pq.x*v0.w + pq.y*v1.w + pq.z*v2.w + pq.w*v3.w;
            }
            kk = kn;
        }
    }
    for (; kk < ke2; ++kk) {
        float4 v0 = vb[(size_t)kk*128 + col];
#pragma unroll
        for (int qi = 0; qi < 8; ++qi) {
            float pk = p[qi][kk];
            o[qi].x += pk*v0.x; o[qi].y += pk*v0.y;
            o[qi].z += pk*v0.z; o[qi].w += pk*v0.w;
        }
    }

    if (half == 1) {
#pragma unroll
        for (int qi = 0; qi < 8; ++qi) otmp[qi][col] = o[qi];
    }
    __syncthreads();
    if (half == 0) {
#pragma unroll
        for (int qi = 0; qi < 8; ++qi) {
            float4 r = otmp[qi][col];
            o[qi].x += r.x; o[qi].y += r.y; o[qi].z += r.z; o[qi].w += r.w;
            o_part[((size_t)kc * 1024 + (b*Q_ + q0 + qi)) * 128 + col] = o[qi];
        }
    }
}

// ---------------------------------------------------------------------------
// finalize: out[row][col] = (Sum_{ch<nch} o_part[ch][row][col]) * rcp(Sum s).
// nch = ceil(vl/64) <= 16.
// ---------------------------------------------------------------------------
__global__ __launch_bounds__(256) void finalize_kernel(
    const float4* __restrict__ o_part, const float* __restrict__ s_part,
    const int* __restrict__ valid_lens, float4* __restrict__ out)
{
    int gid = blockIdx.x * 256 + threadIdx.x;     // [0, 131072)
    int row = gid >> 7, col = gid & 127;
    int b = row >> 8;
    int nch = (valid_lens[b] + 63) >> 6;
    float ssum = 0.f;
    float4 o = make_float4(0.f, 0.f, 0.f, 0.f);
    for (int ch = 0; ch < nch; ++ch) {
        ssum += s_part[(size_t)row * 16 + ch];
        float4 r = o_part[((size_t)ch * 1024 + row) * 128 + col];
        o.x += r.x; o.y += r.y; o.z += r.z; o.w += r.w;
    }
    float rs = __builtin_amdgcn_rcpf(ssum);
    out[gid] = make_float4(o.x*rs, o.y*rs, o.z*rs, o.w*rs);
}

extern "C" void kernel_launch(void* const* d_in, const int* in_sizes, int n_in,
                              void* d_out, int out_size, void* d_ws, size_t ws_size,
                              hipStream_t stream)
{
    const float* q  = (const float*)d_in[0];
    const float* k  = (const float*)d_in[1];
    const float* v  = (const float*)d_in[2];
    const int*   vl = (const int*)d_in[3];
    const float* wq = (const float*)d_in[4];
    const float* wk = (const float*)d_in[5];
    const float* wv = (const float*)d_in[6];
    float* out = (float*)d_out;

    float* qh_s  = (float*)d_ws;                      //  131072 f
    float* kh4   = qh_s  + (size_t)B_*Q_*H_;          //  524288 f
    float* s_prt = kh4   + (size_t)B_*H_*K_;          //   16384 f
    float* o_prt = s_prt + (size_t)B_*Q_*16;          // 8388608 f (32 MB)
    float* psum  = o_prt + (size_t)16*B_*Q_*DV_;      // 5242880 f (21 MB)

    proj_part      <<<dim3(640),  dim3(256), 0, stream>>>(q, k, wq, wk, vl, psum);
    proj_reduce    <<<dim3(640),  dim3(256), 0, stream>>>(psum, vl, qh_s, (float4*)kh4);
    attn_part      <<<dim3(2048), dim3(256), 0, stream>>>(qh_s, (const float4*)kh4, wv, vl, v, s_prt, (float4*)o_prt);
    finalize_kernel<<<dim3(512),  dim3(256), 0, stream>>>((const float4*)o_prt, s_prt, vl, (float4*)out);
}